// Round 7
// baseline (306.887 us; speedup 1.0000x reference)
//
#include <hip/hip_runtime.h>
#include <hip/hip_bf16.h>

typedef __attribute__((ext_vector_type(8))) short v8s;   // 8 x bf16 (4 VGPRs)
typedef __attribute__((ext_vector_type(4))) float v4f;   // float4 / MFMA acc

constexpr int H  = 256;   // hidden channels
constexpr int K2 = 512;   // 2H
constexpr int XS = 72;    // padded LDS stride (bf16 elems) -- fallback kernel
constexpr int WS = 72;

__device__ inline unsigned short f2bf(float f) {         // fp32 -> bf16 bits, RNE
    unsigned int u = __builtin_bit_cast(unsigned int, f);
    u += 0x7FFFu + ((u >> 16) & 1u);
    return (unsigned short)(u >> 16);
}
__device__ inline float bf2f(unsigned short s) {
    return __builtin_bit_cast(float, (unsigned int)s << 16);
}

// ---- pre-kernel: W1 fp32 [512][256] (k-major) -> W1T bf16 [256][512] (n-major) ----
// also zeroes the chunk-flag arrays (block 0) to save a launch
__global__ void w1_transpose_kernel(const float* __restrict__ w1,
                                    unsigned short* __restrict__ w1t,
                                    unsigned char* __restrict__ flags,
                                    const int nflags) {
    __shared__ float tile[32][33];
    const int bk = blockIdx.x;
    const int bn = blockIdx.y;
    const int tx = threadIdx.x & 31;
    const int ty8 = threadIdx.x >> 5;
    if (flags && bk == 0 && bn == 0) {
        for (int i = threadIdx.x; i < nflags; i += 256) flags[i] = 0;
    }
#pragma unroll
    for (int i = 0; i < 4; ++i) {
        int ty = i * 8 + ty8;
        tile[ty][tx] = w1[(size_t)(bk * 32 + ty) * H + bn * 32 + tx];
    }
    __syncthreads();
#pragma unroll
    for (int i = 0; i < 4; ++i) {
        int ty = i * 8 + ty8;
        w1t[(size_t)(bn * 32 + ty) * K2 + bk * 32 + tx] = f2bf(tile[tx][ty]);
    }
}

__global__ void flag_fill_kernel(const int* __restrict__ eli,
                                 unsigned char* __restrict__ fu,
                                 unsigned char* __restrict__ fm,
                                 const int E, const int nu, const int nm) {
    const long stride = (long)blockDim.x * gridDim.x;
    for (long e = threadIdx.x + (long)blockIdx.x * blockDim.x; e < E; e += stride) {
        int u = eli[e];
        int m = eli[(long)E + e];
        u = u < 0 ? 0 : (u >= nu ? nu - 1 : u);   // same clamp as edge_score_kernel
        m = m < 0 ? 0 : (m >= nm ? nm - 1 : m);
        fu[u >> 6] = 1;
        fm[m >> 6] = 1;
    }
}

// ---- persistent fused dense GEMM, v5: fully wave-independent streaming ----
// grid = 256 blocks (1/CU), 512 thr = 8 waves, 2/SIMD. Even blocks: user side.
// B (side of W1T, 256x256 bf16) in registers/AGPRs (loaded once from L2).
// NO LDS, NO barriers, NO manual vmcnt: each wave streams its A-fragments
// straight from global to registers (depth-2 kk prefetch + cross-chunk
// prefetch) and converts fp32->bf16 with v_cvt_pk_bf16_f32 (1 inst / 2 elems).
// R6 evidence: barrier+LDS convoy variants all stall at ~10.4 us/chunk with
// only ~2-3 us of actual work; self-paced waves remove the convoy stall.
__global__ __launch_bounds__(512, 2) void emb_gemm_persist_kernel(
    const float* __restrict__ user_emb,
    const float* __restrict__ movie_emb,
    const unsigned short* __restrict__ w1t, // [256][512] bf16
    const float* __restrict__ b1,           // [256]
    unsigned short* __restrict__ P,         // [(n_users+64)][256] bf16
    unsigned short* __restrict__ Q,         // [(n_movies+64)][256] bf16
    const int n_users, const int n_movies,
    const unsigned char* __restrict__ fu,
    const unsigned char* __restrict__ fm)
{
    const int bid   = blockIdx.x;
    const int nside = (int)(gridDim.x >> 1);          // blocks per side (128)
    const int isMovie = bid & 1;
    const int base  = bid >> 1;

    const float* emb = isMovie ? movie_emb : user_emb;
    unsigned short* outp = isMovie ? Q : P;
    const int M    = isMovie ? n_movies : n_users;
    const int kofs = isMovie ? 256 : 0;
    const int nch  = (M + 63) >> 6;
    const unsigned char* flags = isMovie ? fm : fu;

    const int t    = threadIdx.x;
    const int wave = t >> 6;
    const int lane = t & 63;
    const int wm   = wave >> 2;   // 0..1 : 32-row half
    const int wn   = wave & 3;    // 0..3 : 64-col slice
    const int quad = lane >> 4;
    const int l16  = lane & 15;

    // active-chunk mask, identical in every wave (wave-uniform SGPR value)
    unsigned long long mk;
    {
        int c0 = base + lane * nside;
        bool a = (c0 < nch) && (flags[c0] != 0);
        mk = __ballot(a);
    }
    const int nact = (int)__popcll(mk);
    if (nact == 0) return;

    unsigned long long cur = mk;
    auto nextc = [&](unsigned long long& m) -> int {
        int p = (int)__builtin_ctzll(m);
        m &= m - 1;
        return base + p * nside;
    };

    // ---- B fragments into registers (once; w1t is L2-hot) ----
    v8s B[4][4][2];   // [nt][kt][ks] : 128 regs (VGPR/AGPR unified file)
    {
        const unsigned short* wb = w1t + (size_t)(wn * 64 + l16) * K2 + kofs + quad * 8;
#pragma unroll
        for (int nt = 0; nt < 4; ++nt)
#pragma unroll
            for (int kt = 0; kt < 4; ++kt)
#pragma unroll
                for (int ks = 0; ks < 2; ++ks)
                    B[nt][kt][ks] = *(const v8s*)(wb + (size_t)nt * 16 * K2 + kt * 64 + ks * 32);
    }
    float bv[4];
#pragma unroll
    for (int nt = 0; nt < 4; ++nt)
        bv[nt] = isMovie ? 0.f : b1[wn * 64 + nt * 16 + l16];

    auto KEEPB = [&]() {      // pin B across the loop (identity asm)
#pragma unroll
        for (int nt = 0; nt < 4; ++nt)
#pragma unroll
            for (int kt = 0; kt < 4; ++kt)
#pragma unroll
                for (int ks = 0; ks < 2; ++ks)
                    asm volatile("" : "+v"(B[nt][kt][ks]));
    };

    // per-chunk row base pointers (this wave's 2 row slices)
    const float* pA[2];
    const float* pN[2];
    auto SETP = [&](const float** p, int c) {
#pragma unroll
        for (int mt = 0; mt < 2; ++mt) {
            long r = (long)c * 64 + wm * 32 + mt * 16 + l16;
            if (r >= M) r = M - 1;
            p[mt] = emb + (size_t)r * H;
        }
    };

    v4f xf[2][2][2];   // [buf][mt][half] : 32 VGPRs in flight (depth-2)
    auto LOADA = [&](int b, const float** p, int kk) {
#pragma unroll
        for (int mt = 0; mt < 2; ++mt) {
            const float* s = p[mt] + kk * 32 + quad * 8;
            xf[b][mt][0] = *(const v4f*)(s);
            xf[b][mt][1] = *(const v4f*)(s + 4);
        }
    };
    auto CONV = [&](v8s* af, int b) {
#pragma unroll
        for (int mt = 0; mt < 2; ++mt) {
            union { v8s s; unsigned int w[4]; } u;
            asm("v_cvt_pk_bf16_f32 %0, %1, %2"
                : "=v"(u.w[0]) : "v"(xf[b][mt][0][0]), "v"(xf[b][mt][0][1]));
            asm("v_cvt_pk_bf16_f32 %0, %1, %2"
                : "=v"(u.w[1]) : "v"(xf[b][mt][0][2]), "v"(xf[b][mt][0][3]));
            asm("v_cvt_pk_bf16_f32 %0, %1, %2"
                : "=v"(u.w[2]) : "v"(xf[b][mt][1][0]), "v"(xf[b][mt][1][1]));
            asm("v_cvt_pk_bf16_f32 %0, %1, %2"
                : "=v"(u.w[3]) : "v"(xf[b][mt][1][2]), "v"(xf[b][mt][1][3]));
            af[mt] = u.s;
        }
    };

    // prologue: first chunk's kk=0,1 in flight
    int c = nextc(cur);
    SETP(pA, c);
    LOADA(0, pA, 0);
    LOADA(1, pA, 1);

    for (int j = 0; j < nact; ++j) {
        KEEPB();
        const long m0 = (long)c * 64;
        const int cn = cur ? (base + (int)__builtin_ctzll(cur) * nside) : c; // peek
        SETP(pN, cn);

        v4f acc[2][4];
#pragma unroll
        for (int mt = 0; mt < 2; ++mt)
#pragma unroll
            for (int nt = 0; nt < 4; ++nt)
                acc[mt][nt] = (v4f){0.f, 0.f, 0.f, 0.f};

#pragma unroll
        for (int kk = 0; kk < 8; ++kk) {
            v8s af[2];
            CONV(af, kk & 1);
            if (kk < 6) LOADA(kk & 1, pA, kk + 2);        // depth-2 intra-chunk
            else        LOADA(kk & 1, pN, kk - 6);        // cross-chunk prefetch
#pragma unroll
            for (int mt = 0; mt < 2; ++mt)
#pragma unroll
                for (int nt = 0; nt < 4; ++nt)
                    acc[mt][nt] = __builtin_amdgcn_mfma_f32_16x16x32_bf16(
                        af[mt], B[nt][kk >> 1][kk & 1], acc[mt][nt], 0, 0, 0);
        }

        // epilogue: (+b1 user side), bf16 store; UNIFORM 32 stores/wave (padded P/Q)
#pragma unroll
        for (int mt = 0; mt < 2; ++mt)
#pragma unroll
            for (int j4 = 0; j4 < 4; ++j4) {
                const long m = m0 + wm * 32 + mt * 16 + quad * 4 + j4;
#pragma unroll
                for (int nt = 0; nt < 4; ++nt)
                    outp[(size_t)m * H + wn * 64 + nt * 16 + l16] =
                        f2bf(acc[mt][nt][j4] + bv[nt]);
            }

        pA[0] = pN[0]; pA[1] = pN[1];
        c = cn;
        if (j + 1 < nact) cur &= cur - 1;                 // pop the peeked chunk
    }
}

// ---- edge pass: out[e] = relu(P[u] + Q[m]) . w2 + b2 ----
// block 256 thr = 8 half-waves; each half-wave does 8 edges; row loads double-buffered
// (R1-verified variant). e0 = range offset (pass is split in two for profiling).
__global__ __launch_bounds__(256, 8) void edge_score_kernel(
    const unsigned short* __restrict__ P,
    const unsigned short* __restrict__ Q,
    const int* __restrict__ eli,
    const float* __restrict__ w2,
    const float* __restrict__ b2,
    float* __restrict__ out,
    const int E, const int n_users, const int n_movies, const long e0)
{
    const int t   = threadIdx.x;
    const int hw  = t >> 5;        // 0..7
    const int l32 = t & 31;

    float w2v[8];
    {
        v4f a = *(const v4f*)(w2 + l32 * 8);
        v4f b = *(const v4f*)(w2 + l32 * 8 + 4);
#pragma unroll
        for (int i = 0; i < 4; ++i) { w2v[i] = a[i]; w2v[4 + i] = b[i]; }
    }
    const float b2v = b2[0];
    const long base = e0 + (long)blockIdx.x * 64;

    // preload all 16 indices (independent loads issue together)
    int us[8], ms[8];
#pragma unroll
    for (int i = 0; i < 8; ++i) {
        long e = base + i * 8 + hw;
        long ec = (e < E) ? e : 0;
        int u = eli[ec];
        int m = eli[(long)E + ec];
        us[i] = u < 0 ? 0 : (u >= n_users  ? n_users  - 1 : u);
        ms[i] = m < 0 ? 0 : (m >= n_movies ? n_movies - 1 : m);
    }

    v8s pv = *(const v8s*)(P + (size_t)us[0] * H + l32 * 8);
    v8s qv = *(const v8s*)(Q + (size_t)ms[0] * H + l32 * 8);

#pragma unroll
    for (int i = 0; i < 8; ++i) {
        v8s pn, qn;
        if (i < 7) {                                   // next rows issue before compute
            pn = *(const v8s*)(P + (size_t)us[i + 1] * H + l32 * 8);
            qn = *(const v8s*)(Q + (size_t)ms[i + 1] * H + l32 * 8);
        }
        float s = 0.f;
#pragma unroll
        for (int j = 0; j < 8; ++j) {
            float h = bf2f((unsigned short)pv[j]) + bf2f((unsigned short)qv[j]);
            h = h > 0.f ? h : 0.f;
            s += h * w2v[j];
        }
        s += __shfl_xor(s, 1, 64);
        s += __shfl_xor(s, 2, 64);
        s += __shfl_xor(s, 4, 64);
        s += __shfl_xor(s, 8, 64);
        s += __shfl_xor(s, 16, 64);
        long e = base + i * 8 + hw;
        if (l32 == 0 && e < E) out[e] = s + b2v;
        pv = pn; qv = qn;
    }
}

// ================= round-6 fallback (verified) — used if ws_size too small ==========
constexpr int BMF = 64;
__global__ __launch_bounds__(512, 4) void edge_decoder_kernel(
    const float* __restrict__ user_emb, const float* __restrict__ movie_emb,
    const int* __restrict__ eli, const unsigned short* __restrict__ w1t,
    const float* __restrict__ b1, const float* __restrict__ w2,
    const float* __restrict__ b2, float* __restrict__ out,
    const int E, const int n_users, const int n_movies)
{
    __shared__ unsigned short Xs[BMF * XS];
    __shared__ unsigned short Wts[H * WS];
    __shared__ float red[4][BMF];
    const int t = threadIdx.x, wave = t >> 6, lane = t & 63;
    const int wm = wave >> 2, wn = wave & 3, quad = lane >> 4, l16 = lane & 15;
    const long e0 = (long)blockIdx.x * BMF;
    const int xr = t >> 3, xc = t & 7;
    long eg = e0 + xr; if (eg >= E) eg = 0;
    int iu = eli[eg], im = eli[(long)E + eg];
    iu = iu < 0 ? 0 : (iu >= n_users ? n_users - 1 : iu);
    im = im < 0 ? 0 : (im >= n_movies ? n_movies - 1 : im);
    const float* urow = user_emb + (size_t)iu * H;
    const float* mrow = movie_emb + (size_t)im * H;
    const int wr = t >> 3, wc8 = t & 7;
    const unsigned short* wbase = w1t + (size_t)wr * K2 + wc8 * 8;
    v4f acc[2][4];
#pragma unroll
    for (int mt = 0; mt < 2; ++mt)
#pragma unroll
        for (int nt = 0; nt < 4; ++nt) acc[mt][nt] = (v4f){0.f,0.f,0.f,0.f};
    v4f xq0 = *(const v4f*)(urow + xc * 8);
    v4f xq1 = *(const v4f*)(urow + xc * 8 + 4);
    v8s wq[4];
#pragma unroll
    for (int j = 0; j < 4; ++j) wq[j] = *(const v8s*)(wbase + (size_t)j * 64 * K2);
    for (int kt = 0; kt < 8; ++kt) {
        __syncthreads();
        { v8s xv;
#pragma unroll
          for (int i = 0; i < 4; ++i) xv[i] = (short)f2bf(xq0[i]);
#pragma unroll
          for (int i = 0; i < 4; ++i) xv[4+i] = (short)f2bf(xq1[i]);
          *(v8s*)(Xs + xr * XS + xc * 8) = xv; }
#pragma unroll
        for (int j = 0; j < 4; ++j) *(v8s*)(Wts + (j * 64 + wr) * WS + wc8 * 8) = wq[j];
        if (kt < 7) {
            const int kn = kt + 1, koff = (kn * 64) & 255;
            const float* src = ((kn < 4) ? urow : mrow) + koff + xc * 8;
            xq0 = *(const v4f*)(src); xq1 = *(const v4f*)(src + 4);
#pragma unroll
            for (int j = 0; j < 4; ++j) wq[j] = *(const v8s*)(wbase + (size_t)j * 64 * K2 + kn * 64);
        }
        __syncthreads();
#pragma unroll
        for (int ks = 0; ks < 2; ++ks) {
            v8s af[2], bf[4];
#pragma unroll
            for (int mt = 0; mt < 2; ++mt)
                af[mt] = *(const v8s*)(Xs + (wm * 32 + mt * 16 + l16) * XS + ks * 32 + quad * 8);
#pragma unroll
            for (int nt = 0; nt < 4; ++nt)
                bf[nt] = *(const v8s*)(Wts + (wn * 64 + nt * 16 + l16) * WS + ks * 32 + quad * 8);
#pragma unroll
            for (int mt = 0; mt < 2; ++mt)
#pragma unroll
                for (int nt = 0; nt < 4; ++nt)
                    acc[mt][nt] = __builtin_amdgcn_mfma_f32_16x16x32_bf16(af[mt], bf[nt], acc[mt][nt], 0, 0, 0);
        }
    }
    float b1v[4], w2v[4];
#pragma unroll
    for (int nt = 0; nt < 4; ++nt) {
        int n = wn * 64 + nt * 16 + l16;
        b1v[nt] = b1[n]; w2v[nt] = w2[n];
    }
    const float b2v = b2[0];
#pragma unroll
    for (int mt = 0; mt < 2; ++mt) {
        float s[4] = {0.f,0.f,0.f,0.f};
#pragma unroll
        for (int nt = 0; nt < 4; ++nt)
#pragma unroll
            for (int j = 0; j < 4; ++j) {
                float h = acc[mt][nt][j] + b1v[nt];
                h = h > 0.f ? h : 0.f;
                s[j] += h * w2v[nt];
            }
#pragma unroll
        for (int j = 0; j < 4; ++j) {
            float v = s[j];
            v += __shfl_xor(v, 1, 64); v += __shfl_xor(v, 2, 64);
            v += __shfl_xor(v, 4, 64); v += __shfl_xor(v, 8, 64);
            if (l16 == 0) red[wn][wm * 32 + mt * 16 + quad * 4 + j] = v;
        }
    }
    __syncthreads();
    if (t < BMF) {
        long e = e0 + t;
        if (e < E) out[e] = red[0][t] + red[1][t] + red[2][t] + red[3][t] + b2v;
    }
}

extern "C" void kernel_launch(void* const* d_in, const int* in_sizes, int n_in,
                              void* d_out, int out_size, void* d_ws, size_t ws_size,
                              hipStream_t stream) {
    const float* user_emb  = (const float*)d_in[0];
    const float* movie_emb = (const float*)d_in[1];
    const int*   eli       = (const int*)d_in[2];
    const float* w1        = (const float*)d_in[3];
    const float* b1        = (const float*)d_in[4];
    const float* w2        = (const float*)d_in[5];
    const float* b2        = (const float*)d_in[6];
    float*       out       = (float*)d_out;

    const int E        = out_size;
    const int n_users  = in_sizes[0] / H;
    const int n_movies = in_sizes[1] / H;

    unsigned short* w1t = (unsigned short*)d_ws;                 // 256 KiB
    const size_t w1t_bytes = (size_t)K2 * H * 2;
    const size_t p_bytes   = (size_t)(n_users  + 64) * H * 2;    // +64 pad rows
    const size_t q_bytes   = (size_t)(n_movies + 64) * H * 2;    // (uniform epilogue)

    const int nbu = (n_users  + 63) / 64;
    const int nbm = (n_movies + 63) / 64;
    const size_t flag_bytes = (size_t)nbu + (size_t)nbm;

    // persistent path needs: w1t + padded P + padded Q + flags, and chunk counts
    // within the per-block ballot capacity (64 mask bits x 128 blocks/side)
    if (ws_size >= w1t_bytes + p_bytes + q_bytes + flag_bytes &&
        nbu <= 64 * 128 && nbm <= 64 * 128) {
        unsigned short* P = (unsigned short*)((char*)d_ws + w1t_bytes);
        unsigned short* Q = (unsigned short*)((char*)d_ws + w1t_bytes + p_bytes);
        unsigned char*  fu = (unsigned char*)((char*)d_ws + w1t_bytes + p_bytes + q_bytes);
        unsigned char*  fm = fu + nbu;

        w1_transpose_kernel<<<dim3(16, 8), 256, 0, stream>>>(w1, w1t, fu, nbu + nbm);
        if (E > 0)
            flag_fill_kernel<<<512, 256, 0, stream>>>(eli, fu, fm, E, n_users, n_movies);
        emb_gemm_persist_kernel<<<256, 512, 0, stream>>>(
            user_emb, movie_emb, w1t, b1, P, Q, n_users, n_movies, fu, fm);
        if (E > 0) {
            // split in two dispatches so the GEMM stays visible in the profile top-5
            long Eh = ((long)(E / 2) + 63) & ~63L;
            if (Eh > E) Eh = E;
            if (Eh > 0)
                edge_score_kernel<<<(int)(Eh / 64), 256, 0, stream>>>(
                    P, Q, eli, w2, b2, out, E, n_users, n_movies, 0);
            if (E - Eh > 0)
                edge_score_kernel<<<(int)((E - Eh + 63) / 64), 256, 0, stream>>>(
                    P, Q, eli, w2, b2, out, E, n_users, n_movies, Eh);
        }
    } else {
        w1_transpose_kernel<<<dim3(16, 8), 256, 0, stream>>>(w1, w1t, nullptr, 0);
        if (E > 0)
            edge_decoder_kernel<<<(E + BMF - 1) / BMF, 512, 0, stream>>>(
                user_emb, movie_emb, eli, w1t, b1, w2, b2, out, E, n_users, n_movies);
    }
}

// Round 8
// 268.093 us; speedup vs baseline: 1.1447x; 1.1447x over previous
//
#include <hip/hip_runtime.h>
#include <hip/hip_bf16.h>

typedef __attribute__((ext_vector_type(8))) short v8s;   // 8 x bf16 (4 VGPRs)
typedef __attribute__((ext_vector_type(4))) float v4f;   // float4 / MFMA acc

constexpr int H  = 256;   // hidden channels
constexpr int K2 = 512;   // 2H
constexpr int XS = 72;    // padded LDS stride (bf16 elems) -- fallback kernel
constexpr int WS = 72;

__device__ inline unsigned short f2bf(float f) {         // fp32 -> bf16 bits, RNE
    unsigned int u = __builtin_bit_cast(unsigned int, f);
    u += 0x7FFFu + ((u >> 16) & 1u);
    return (unsigned short)(u >> 16);
}
__device__ inline float bf2f(unsigned short s) {
    return __builtin_bit_cast(float, (unsigned int)s << 16);
}

#define SB() __builtin_amdgcn_sched_barrier(0)
#define VMW(N) do { asm volatile("s_waitcnt vmcnt(" #N ")" ::: "memory"); SB(); } while (0)

// ---- pre-kernel: W1 fp32 [512][256] (k-major) -> W1T bf16 [256][512] (n-major) ----
// also zeroes the chunk-flag arrays (block 0) to save a launch
__global__ void w1_transpose_kernel(const float* __restrict__ w1,
                                    unsigned short* __restrict__ w1t,
                                    unsigned char* __restrict__ flags,
                                    const int nflags) {
    __shared__ float tile[32][33];
    const int bk = blockIdx.x;
    const int bn = blockIdx.y;
    const int tx = threadIdx.x & 31;
    const int ty8 = threadIdx.x >> 5;
    if (flags && bk == 0 && bn == 0) {
        for (int i = threadIdx.x; i < nflags; i += 256) flags[i] = 0;
    }
#pragma unroll
    for (int i = 0; i < 4; ++i) {
        int ty = i * 8 + ty8;
        tile[ty][tx] = w1[(size_t)(bk * 32 + ty) * H + bn * 32 + tx];
    }
    __syncthreads();
#pragma unroll
    for (int i = 0; i < 4; ++i) {
        int ty = i * 8 + ty8;
        w1t[(size_t)(bn * 32 + ty) * K2 + bk * 32 + tx] = f2bf(tile[tx][ty]);
    }
}

__global__ void flag_fill_kernel(const int* __restrict__ eli,
                                 unsigned char* __restrict__ fu,
                                 unsigned char* __restrict__ fm,
                                 const int E, const int nu, const int nm) {
    const long stride = (long)blockDim.x * gridDim.x;
    for (long e = threadIdx.x + (long)blockIdx.x * blockDim.x; e < E; e += stride) {
        int u = eli[e];
        int m = eli[(long)E + e];
        u = u < 0 ? 0 : (u >= nu ? nu - 1 : u);   // same clamp as edge_score_kernel
        m = m < 0 ? 0 : (m >= nm ? nm - 1 : m);
        fu[u >> 6] = 1;
        fm[m >> 6] = 1;
    }
}

// ---- persistent fused dense GEMM, v6: 16 waves/CU, 32x32 wave tile ----
// grid = 256 blocks (1/CU), 1024 thr = 16 waves = 4/SIMD (combined reg ~115).
// Even blocks: user side, odd: movie. B slice per wave = 32 cols x 256 k =
// 64 regs (AGPR-friendly, loaded once from L2). X (fp32 rows) staged to a
// 2x64KiB LDS double buffer via global_load_lds width=16 (4 rows/wave,
// source XOR-preswizzled); v_cvt_pk_bf16_f32 on the read path (R7-validated).
// Counted vmcnt 4/20/16 -- never 0 in steady state -- loads stay in flight
// across both barriers. R1/R5/R6 all plateau at ~62us with 8 waves/CU across
// three staging structures; this isolates the TLP axis at fixed staging.
__global__ __launch_bounds__(1024, 4) void emb_gemm_persist_kernel(
    const float* __restrict__ user_emb,
    const float* __restrict__ movie_emb,
    const unsigned short* __restrict__ w1t, // [256][512] bf16
    const float* __restrict__ b1,           // [256]
    unsigned short* __restrict__ P,         // [(n_users+64)][256] bf16
    unsigned short* __restrict__ Q,         // [(n_movies+64)][256] bf16
    const int n_users, const int n_movies,
    const unsigned char* __restrict__ fu,
    const unsigned char* __restrict__ fm)
{
    __shared__ __align__(16) char Xs[2][64][1024];   // fp32 rows, 128 KiB total

    const int bid   = blockIdx.x;
    const int nside = (int)(gridDim.x >> 1);          // blocks per side (128)
    const int isMovie = bid & 1;
    const int base  = bid >> 1;

    const float* emb = isMovie ? movie_emb : user_emb;
    unsigned short* outp = isMovie ? Q : P;
    const int M    = isMovie ? n_movies : n_users;
    const int kofs = isMovie ? 256 : 0;
    const int nch  = (M + 63) >> 6;
    const unsigned char* flags = isMovie ? fm : fu;

    const int t    = threadIdx.x;
    const int wave = t >> 6;      // 0..15
    const int lane = t & 63;
    const int wm   = wave >> 3;   // 0..1 : 32-row half
    const int wn   = wave & 7;    // 0..7 : 32-col slice
    const int quad = lane >> 4;
    const int l16  = lane & 15;

    // active-chunk mask, identical in every wave (wave-uniform SGPR value)
    unsigned long long mk;
    {
        int c0 = base + lane * nside;
        bool a = (c0 < nch) && (flags[c0] != 0);
        mk = __ballot(a);
    }
    const int nact = (int)__popcll(mk);
    if (nact == 0) return;

    unsigned long long cur = mk, pf = mk;
    auto nextc = [&](unsigned long long& m) -> int {
        int p = (int)__builtin_ctzll(m);
        m &= m - 1;
        return base + p * nside;
    };

    // ---- B fragments (32-col slice) into regs/AGPRs: 64 regs/lane, once ----
    v8s B[2][4][2];   // [nt][kt][ks]
    {
        const unsigned short* wb = w1t + (size_t)(wn * 32 + l16) * K2 + kofs + quad * 8;
#pragma unroll
        for (int nt = 0; nt < 2; ++nt)
#pragma unroll
            for (int kt = 0; kt < 4; ++kt)
#pragma unroll
                for (int ks = 0; ks < 2; ++ks)
                    B[nt][kt][ks] = *(const v8s*)(wb + (size_t)nt * 16 * K2 + kt * 64 + ks * 32);
    }
    float bv[2];
#pragma unroll
    for (int nt = 0; nt < 2; ++nt)
        bv[nt] = isMovie ? 0.f : b1[wn * 32 + nt * 16 + l16];
    SB();

    // stage one chunk's fp32 rows into LDS buffer b: 4 rows per wave, 1 KiB each,
    // source pre-swizzled so the ds_read side can XOR with (row&7)<<4
    auto STAGE = [&](int c, int b) {
#pragma unroll
        for (int i = 0; i < 4; ++i) {
            const int rl = wave * 4 + i;
            long r = (long)c * 64 + rl;
            if (r >= M) r = M - 1;
            const char* src = (const char*)(emb + (size_t)r * H) + ((lane * 16) ^ ((rl & 7) << 4));
            __builtin_amdgcn_global_load_lds(
                (const __attribute__((address_space(1))) unsigned int*)src,
                (__attribute__((address_space(3))) unsigned int*)&Xs[b][rl][0],
                16, 0, 0);
        }
        SB();
    };

    STAGE(nextc(pf), 0);
    if (nact > 1) STAGE(nextc(pf), 1);

    for (int j = 0; j < nact; ++j) {
        const int cb = j & 1;
        const long m0 = (long)nextc(cur) * 64;

        // wait for buf[cb]'s 4 loads (counted: leave younger ops in flight).
        // younger: j==0 -> 4 loads of c1 (if any);
        // j>=1 -> 16 epilogue stores of iter j-1 (+4 loads of c[j+1] if issued).
        if (j == 0) { if (nact > 1) VMW(4); else VMW(0); }
        else        { if (j + 1 < nact) VMW(20); else VMW(16); }
        __builtin_amdgcn_s_barrier(); SB();

        v4f acc[2][2];
#pragma unroll
        for (int mt = 0; mt < 2; ++mt)
#pragma unroll
            for (int nt = 0; nt < 2; ++nt)
                acc[mt][nt] = (v4f){0.f, 0.f, 0.f, 0.f};

        const char* xb = &Xs[cb][0][0];
#pragma unroll
        for (int kk = 0; kk < 8; ++kk) {
            v8s af[2];
#pragma unroll
            for (int mt = 0; mt < 2; ++mt) {
                const int row = wm * 32 + mt * 16 + l16;
                const int sw  = (row & 7) << 4;
                const char* pr = xb + row * 1024;
                v4f f0 = *(const v4f*)(pr + ((kk * 128 + quad * 32) ^ sw));
                v4f f1 = *(const v4f*)(pr + ((kk * 128 + quad * 32 + 16) ^ sw));
                union { v8s s; unsigned int w[4]; } u;
                asm("v_cvt_pk_bf16_f32 %0, %1, %2" : "=v"(u.w[0]) : "v"(f0[0]), "v"(f0[1]));
                asm("v_cvt_pk_bf16_f32 %0, %1, %2" : "=v"(u.w[1]) : "v"(f0[2]), "v"(f0[3]));
                asm("v_cvt_pk_bf16_f32 %0, %1, %2" : "=v"(u.w[2]) : "v"(f1[0]), "v"(f1[1]));
                asm("v_cvt_pk_bf16_f32 %0, %1, %2" : "=v"(u.w[3]) : "v"(f1[2]), "v"(f1[3]));
                af[mt] = u.s;
            }
#pragma unroll
            for (int mt = 0; mt < 2; ++mt)
#pragma unroll
                for (int nt = 0; nt < 2; ++nt)
                    acc[mt][nt] = __builtin_amdgcn_mfma_f32_16x16x32_bf16(
                        af[mt], B[nt][kk >> 1][kk & 1], acc[mt][nt], 0, 0, 0);
        }

        // epilogue: (+b1 user side), bf16 store; UNIFORM 16 stores/wave (padded P/Q)
#pragma unroll
        for (int mt = 0; mt < 2; ++mt)
#pragma unroll
            for (int j4 = 0; j4 < 4; ++j4) {
                const long m = m0 + wm * 32 + mt * 16 + quad * 4 + j4;
#pragma unroll
                for (int nt = 0; nt < 2; ++nt)
                    outp[(size_t)m * H + wn * 32 + nt * 16 + l16] =
                        f2bf(acc[mt][nt][j4] + bv[nt]);
            }
        SB();
        __builtin_amdgcn_s_barrier(); SB();
        if (j + 2 < nact) STAGE(nextc(pf), cb);   // reuse buf[cb]; stays in flight
    }
}

// ---- edge pass: out[e] = relu(P[u] + Q[m]) . w2 + b2 ----
// block 256 thr = 8 half-waves; each half-wave does 8 edges; row loads double-buffered
// (R1-verified variant). e0 = range offset (pass is split in two for profiling).
__global__ __launch_bounds__(256, 8) void edge_score_kernel(
    const unsigned short* __restrict__ P,
    const unsigned short* __restrict__ Q,
    const int* __restrict__ eli,
    const float* __restrict__ w2,
    const float* __restrict__ b2,
    float* __restrict__ out,
    const int E, const int n_users, const int n_movies, const long e0)
{
    const int t   = threadIdx.x;
    const int hw  = t >> 5;        // 0..7
    const int l32 = t & 31;

    float w2v[8];
    {
        v4f a = *(const v4f*)(w2 + l32 * 8);
        v4f b = *(const v4f*)(w2 + l32 * 8 + 4);
#pragma unroll
        for (int i = 0; i < 4; ++i) { w2v[i] = a[i]; w2v[4 + i] = b[i]; }
    }
    const float b2v = b2[0];
    const long base = e0 + (long)blockIdx.x * 64;

    // preload all 16 indices (independent loads issue together)
    int us[8], ms[8];
#pragma unroll
    for (int i = 0; i < 8; ++i) {
        long e = base + i * 8 + hw;
        long ec = (e < E) ? e : 0;
        int u = eli[ec];
        int m = eli[(long)E + ec];
        us[i] = u < 0 ? 0 : (u >= n_users  ? n_users  - 1 : u);
        ms[i] = m < 0 ? 0 : (m >= n_movies ? n_movies - 1 : m);
    }

    v8s pv = *(const v8s*)(P + (size_t)us[0] * H + l32 * 8);
    v8s qv = *(const v8s*)(Q + (size_t)ms[0] * H + l32 * 8);

#pragma unroll
    for (int i = 0; i < 8; ++i) {
        v8s pn, qn;
        if (i < 7) {                                   // next rows issue before compute
            pn = *(const v8s*)(P + (size_t)us[i + 1] * H + l32 * 8);
            qn = *(const v8s*)(Q + (size_t)ms[i + 1] * H + l32 * 8);
        }
        float s = 0.f;
#pragma unroll
        for (int j = 0; j < 8; ++j) {
            float h = bf2f((unsigned short)pv[j]) + bf2f((unsigned short)qv[j]);
            h = h > 0.f ? h : 0.f;
            s += h * w2v[j];
        }
        s += __shfl_xor(s, 1, 64);
        s += __shfl_xor(s, 2, 64);
        s += __shfl_xor(s, 4, 64);
        s += __shfl_xor(s, 8, 64);
        s += __shfl_xor(s, 16, 64);
        long e = base + i * 8 + hw;
        if (l32 == 0 && e < E) out[e] = s + b2v;
        pv = pn; qv = qn;
    }
}

// ================= round-6 fallback (verified) — used if ws_size too small ==========
constexpr int BMF = 64;
__global__ __launch_bounds__(512, 4) void edge_decoder_kernel(
    const float* __restrict__ user_emb, const float* __restrict__ movie_emb,
    const int* __restrict__ eli, const unsigned short* __restrict__ w1t,
    const float* __restrict__ b1, const float* __restrict__ w2,
    const float* __restrict__ b2, float* __restrict__ out,
    const int E, const int n_users, const int n_movies)
{
    __shared__ unsigned short Xs[BMF * XS];
    __shared__ unsigned short Wts[H * WS];
    __shared__ float red[4][BMF];
    const int t = threadIdx.x, wave = t >> 6, lane = t & 63;
    const int wm = wave >> 2, wn = wave & 3, quad = lane >> 4, l16 = lane & 15;
    const long e0 = (long)blockIdx.x * BMF;
    const int xr = t >> 3, xc = t & 7;
    long eg = e0 + xr; if (eg >= E) eg = 0;
    int iu = eli[eg], im = eli[(long)E + eg];
    iu = iu < 0 ? 0 : (iu >= n_users ? n_users - 1 : iu);
    im = im < 0 ? 0 : (im >= n_movies ? n_movies - 1 : im);
    const float* urow = user_emb + (size_t)iu * H;
    const float* mrow = movie_emb + (size_t)im * H;
    const int wr = t >> 3, wc8 = t & 7;
    const unsigned short* wbase = w1t + (size_t)wr * K2 + wc8 * 8;
    v4f acc[2][4];
#pragma unroll
    for (int mt = 0; mt < 2; ++mt)
#pragma unroll
        for (int nt = 0; nt < 4; ++nt) acc[mt][nt] = (v4f){0.f,0.f,0.f,0.f};
    v4f xq0 = *(const v4f*)(urow + xc * 8);
    v4f xq1 = *(const v4f*)(urow + xc * 8 + 4);
    v8s wq[4];
#pragma unroll
    for (int j = 0; j < 4; ++j) wq[j] = *(const v8s*)(wbase + (size_t)j * 64 * K2);
    for (int kt = 0; kt < 8; ++kt) {
        __syncthreads();
        { v8s xv;
#pragma unroll
          for (int i = 0; i < 4; ++i) xv[i] = (short)f2bf(xq0[i]);
#pragma unroll
          for (int i = 0; i < 4; ++i) xv[4+i] = (short)f2bf(xq1[i]);
          *(v8s*)(Xs + xr * XS + xc * 8) = xv; }
#pragma unroll
        for (int j = 0; j < 4; ++j) *(v8s*)(Wts + (j * 64 + wr) * WS + wc8 * 8) = wq[j];
        if (kt < 7) {
            const int kn = kt + 1, koff = (kn * 64) & 255;
            const float* src = ((kn < 4) ? urow : mrow) + koff + xc * 8;
            xq0 = *(const v4f*)(src); xq1 = *(const v4f*)(src + 4);
#pragma unroll
            for (int j = 0; j < 4; ++j) wq[j] = *(const v8s*)(wbase + (size_t)j * 64 * K2 + kn * 64);
        }
        __syncthreads();
#pragma unroll
        for (int ks = 0; ks < 2; ++ks) {
            v8s af[2], bf[4];
#pragma unroll
            for (int mt = 0; mt < 2; ++mt)
                af[mt] = *(const v8s*)(Xs + (wm * 32 + mt * 16 + l16) * XS + ks * 32 + quad * 8);
#pragma unroll
            for (int nt = 0; nt < 4; ++nt)
                bf[nt] = *(const v8s*)(Wts + (wn * 64 + nt * 16 + l16) * WS + ks * 32 + quad * 8);
#pragma unroll
            for (int mt = 0; mt < 2; ++mt)
#pragma unroll
                for (int nt = 0; nt < 4; ++nt)
                    acc[mt][nt] = __builtin_amdgcn_mfma_f32_16x16x32_bf16(af[mt], bf[nt], acc[mt][nt], 0, 0, 0);
        }
    }
    float b1v[4], w2v[4];
#pragma unroll
    for (int nt = 0; nt < 4; ++nt) {
        int n = wn * 64 + nt * 16 + l16;
        b1v[nt] = b1[n]; w2v[nt] = w2[n];
    }
    const float b2v = b2[0];
#pragma unroll
    for (int mt = 0; mt < 2; ++mt) {
        float s[4] = {0.f,0.f,0.f,0.f};
#pragma unroll
        for (int nt = 0; nt < 4; ++nt)
#pragma unroll
            for (int j = 0; j < 4; ++j) {
                float h = acc[mt][nt][j] + b1v[nt];
                h = h > 0.f ? h : 0.f;
                s[j] += h * w2v[nt];
            }
#pragma unroll
        for (int j = 0; j < 4; ++j) {
            float v = s[j];
            v += __shfl_xor(v, 1, 64); v += __shfl_xor(v, 2, 64);
            v += __shfl_xor(v, 4, 64); v += __shfl_xor(v, 8, 64);
            if (l16 == 0) red[wn][wm * 32 + mt * 16 + quad * 4 + j] = v;
        }
    }
    __syncthreads();
    if (t < BMF) {
        long e = e0 + t;
        if (e < E) out[e] = red[0][t] + red[1][t] + red[2][t] + red[3][t] + b2v;
    }
}

extern "C" void kernel_launch(void* const* d_in, const int* in_sizes, int n_in,
                              void* d_out, int out_size, void* d_ws, size_t ws_size,
                              hipStream_t stream) {
    const float* user_emb  = (const float*)d_in[0];
    const float* movie_emb = (const float*)d_in[1];
    const int*   eli       = (const int*)d_in[2];
    const float* w1        = (const float*)d_in[3];
    const float* b1        = (const float*)d_in[4];
    const float* w2        = (const float*)d_in[5];
    const float* b2        = (const float*)d_in[6];
    float*       out       = (float*)d_out;

    const int E        = out_size;
    const int n_users  = in_sizes[0] / H;
    const int n_movies = in_sizes[1] / H;

    unsigned short* w1t = (unsigned short*)d_ws;                 // 256 KiB
    const size_t w1t_bytes = (size_t)K2 * H * 2;
    const size_t p_bytes   = (size_t)(n_users  + 64) * H * 2;    // +64 pad rows
    const size_t q_bytes   = (size_t)(n_movies + 64) * H * 2;    // (uniform epilogue)

    const int nbu = (n_users  + 63) / 64;
    const int nbm = (n_movies + 63) / 64;
    const size_t flag_bytes = (size_t)nbu + (size_t)nbm;

    // persistent path needs: w1t + padded P + padded Q + flags, and chunk counts
    // within the per-block ballot capacity (64 mask bits x 128 blocks/side)
    if (ws_size >= w1t_bytes + p_bytes + q_bytes + flag_bytes &&
        nbu <= 64 * 128 && nbm <= 64 * 128) {
        unsigned short* P = (unsigned short*)((char*)d_ws + w1t_bytes);
        unsigned short* Q = (unsigned short*)((char*)d_ws + w1t_bytes + p_bytes);
        unsigned char*  fu = (unsigned char*)((char*)d_ws + w1t_bytes + p_bytes + q_bytes);
        unsigned char*  fm = fu + nbu;

        w1_transpose_kernel<<<dim3(16, 8), 256, 0, stream>>>(w1, w1t, fu, nbu + nbm);
        if (E > 0)
            flag_fill_kernel<<<512, 256, 0, stream>>>(eli, fu, fm, E, n_users, n_movies);
        emb_gemm_persist_kernel<<<256, 1024, 0, stream>>>(
            user_emb, movie_emb, w1t, b1, P, Q, n_users, n_movies, fu, fm);
        if (E > 0) {
            // split in two dispatches so the GEMM stays visible in the profile top-5
            long Eh = ((long)(E / 2) + 63) & ~63L;
            if (Eh > E) Eh = E;
            if (Eh > 0)
                edge_score_kernel<<<(int)(Eh / 64), 256, 0, stream>>>(
                    P, Q, eli, w2, b2, out, E, n_users, n_movies, 0);
            if (E - Eh > 0)
                edge_score_kernel<<<(int)((E - Eh + 63) / 64), 256, 0, stream>>>(
                    P, Q, eli, w2, b2, out, E, n_users, n_movies, Eh);
        }
    } else {
        w1_transpose_kernel<<<dim3(16, 8), 256, 0, stream>>>(w1, w1t, nullptr, 0);
        if (E > 0)
            edge_decoder_kernel<<<(E + BMF - 1) / BMF, 512, 0, stream>>>(
                user_emb, movie_emb, eli, w1t, b1, w2, b2, out, E, n_users, n_movies);
    }
}

// Round 9
// 265.976 us; speedup vs baseline: 1.1538x; 1.0080x over previous
//
#include <hip/hip_runtime.h>
#include <hip/hip_bf16.h>

typedef __attribute__((ext_vector_type(8))) short v8s;   // 8 x bf16 (4 VGPRs)
typedef __attribute__((ext_vector_type(4))) float v4f;   // float4 / MFMA acc

constexpr int H  = 256;   // hidden channels
constexpr int K2 = 512;   // 2H
constexpr int XS = 72;    // padded LDS stride (bf16 elems) -- fallback kernel
constexpr int WS = 72;

__device__ inline unsigned short f2bf(float f) {         // fp32 -> bf16 bits, RNE
    unsigned int u = __builtin_bit_cast(unsigned int, f);
    u += 0x7FFFu + ((u >> 16) & 1u);
    return (unsigned short)(u >> 16);
}
__device__ inline float bf2f(unsigned short s) {
    return __builtin_bit_cast(float, (unsigned int)s << 16);
}

#define SB() __builtin_amdgcn_sched_barrier(0)
#define VMW(N) do { asm volatile("s_waitcnt vmcnt(" #N ")" ::: "memory"); SB(); } while (0)

// ---- pre-kernel: W1 fp32 [512][256] (k-major) -> W1T bf16 [256][512] (n-major) ----
// also zeroes the chunk-flag arrays (block 0) to save a launch
__global__ void w1_transpose_kernel(const float* __restrict__ w1,
                                    unsigned short* __restrict__ w1t,
                                    unsigned char* __restrict__ flags,
                                    const int nflags) {
    __shared__ float tile[32][33];
    const int bk = blockIdx.x;
    const int bn = blockIdx.y;
    const int tx = threadIdx.x & 31;
    const int ty8 = threadIdx.x >> 5;
    if (flags && bk == 0 && bn == 0) {
        for (int i = threadIdx.x; i < nflags; i += 256) flags[i] = 0;
    }
#pragma unroll
    for (int i = 0; i < 4; ++i) {
        int ty = i * 8 + ty8;
        tile[ty][tx] = w1[(size_t)(bk * 32 + ty) * H + bn * 32 + tx];
    }
    __syncthreads();
#pragma unroll
    for (int i = 0; i < 4; ++i) {
        int ty = i * 8 + ty8;
        w1t[(size_t)(bn * 32 + ty) * K2 + bk * 32 + tx] = f2bf(tile[tx][ty]);
    }
}

__global__ void flag_fill_kernel(const int* __restrict__ eli,
                                 unsigned char* __restrict__ fu,
                                 unsigned char* __restrict__ fm,
                                 const int E, const int nu, const int nm) {
    const long stride = (long)blockDim.x * gridDim.x;
    for (long e = threadIdx.x + (long)blockIdx.x * blockDim.x; e < E; e += stride) {
        int u = eli[e];
        int m = eli[(long)E + e];
        u = u < 0 ? 0 : (u >= nu ? nu - 1 : u);   // same clamp as edge_score_kernel
        m = m < 0 ? 0 : (m >= nm ? nm - 1 : m);
        fu[u >> 6] = 1;
        fm[m >> 6] = 1;
    }
}

// ---- persistent fused dense GEMM, v6 (R8-verified best): 16 waves/CU, 32x32 tile ----
// grid = 256 blocks (1/CU), 1024 thr = 16 waves = 4/SIMD. Even blocks: user side.
// B slice per wave = 32 cols x 256 k = 64 regs (AGPR-resident, loaded once from L2).
// X (fp32 rows) staged to a 2x64KiB LDS double buffer via global_load_lds width=16
// (4 rows/wave, source XOR-preswizzled); v_cvt_pk_bf16_f32 on the read path.
// Counted vmcnt 4/20/16 -- never 0 in steady state. Measured ~58us (R8).
// NOTE (session finding): per-64-row-chunk cadence is ~9.5us/CU and invariant
// across 4-blk/CU, 8-wave, 16-wave, and three staging mechanisms; HBM 20%,
// VALU 18%, MFMA 8% -- the serializer is not visible in available PMCs.
__global__ __launch_bounds__(1024, 4) void emb_gemm_persist_kernel(
    const float* __restrict__ user_emb,
    const float* __restrict__ movie_emb,
    const unsigned short* __restrict__ w1t, // [256][512] bf16
    const float* __restrict__ b1,           // [256]
    unsigned short* __restrict__ P,         // [(n_users+64)][256] bf16
    unsigned short* __restrict__ Q,         // [(n_movies+64)][256] bf16
    const int n_users, const int n_movies,
    const unsigned char* __restrict__ fu,
    const unsigned char* __restrict__ fm)
{
    __shared__ __align__(16) char Xs[2][64][1024];   // fp32 rows, 128 KiB total

    const int bid   = blockIdx.x;
    const int nside = (int)(gridDim.x >> 1);          // blocks per side (128)
    const int isMovie = bid & 1;
    const int base  = bid >> 1;

    const float* emb = isMovie ? movie_emb : user_emb;
    unsigned short* outp = isMovie ? Q : P;
    const int M    = isMovie ? n_movies : n_users;
    const int kofs = isMovie ? 256 : 0;
    const int nch  = (M + 63) >> 6;
    const unsigned char* flags = isMovie ? fm : fu;

    const int t    = threadIdx.x;
    const int wave = t >> 6;      // 0..15
    const int lane = t & 63;
    const int wm   = wave >> 3;   // 0..1 : 32-row half
    const int wn   = wave & 7;    // 0..7 : 32-col slice
    const int quad = lane >> 4;
    const int l16  = lane & 15;

    // active-chunk mask, identical in every wave (wave-uniform SGPR value)
    unsigned long long mk;
    {
        int c0 = base + lane * nside;
        bool a = (c0 < nch) && (flags[c0] != 0);
        mk = __ballot(a);
    }
    const int nact = (int)__popcll(mk);
    if (nact == 0) return;

    unsigned long long cur = mk, pf = mk;
    auto nextc = [&](unsigned long long& m) -> int {
        int p = (int)__builtin_ctzll(m);
        m &= m - 1;
        return base + p * nside;
    };

    // ---- B fragments (32-col slice) into regs/AGPRs: 64 regs/lane, once ----
    v8s B[2][4][2];   // [nt][kt][ks]
    {
        const unsigned short* wb = w1t + (size_t)(wn * 32 + l16) * K2 + kofs + quad * 8;
#pragma unroll
        for (int nt = 0; nt < 2; ++nt)
#pragma unroll
            for (int kt = 0; kt < 4; ++kt)
#pragma unroll
                for (int ks = 0; ks < 2; ++ks)
                    B[nt][kt][ks] = *(const v8s*)(wb + (size_t)nt * 16 * K2 + kt * 64 + ks * 32);
    }
    float bv[2];
#pragma unroll
    for (int nt = 0; nt < 2; ++nt)
        bv[nt] = isMovie ? 0.f : b1[wn * 32 + nt * 16 + l16];
    SB();

    // stage one chunk's fp32 rows into LDS buffer b: 4 rows per wave, 1 KiB each,
    // source pre-swizzled so the ds_read side can XOR with (row&7)<<4
    auto STAGE = [&](int c, int b) {
#pragma unroll
        for (int i = 0; i < 4; ++i) {
            const int rl = wave * 4 + i;
            long r = (long)c * 64 + rl;
            if (r >= M) r = M - 1;
            const char* src = (const char*)(emb + (size_t)r * H) + ((lane * 16) ^ ((rl & 7) << 4));
            __builtin_amdgcn_global_load_lds(
                (const __attribute__((address_space(1))) unsigned int*)src,
                (__attribute__((address_space(3))) unsigned int*)&Xs[b][rl][0],
                16, 0, 0);
        }
        SB();
    };

    STAGE(nextc(pf), 0);
    if (nact > 1) STAGE(nextc(pf), 1);

    for (int j = 0; j < nact; ++j) {
        const int cb = j & 1;
        const long m0 = (long)nextc(cur) * 64;

        // wait for buf[cb]'s 4 loads (counted: leave younger ops in flight).
        // younger: j==0 -> 4 loads of c1 (if any);
        // j>=1 -> 16 epilogue stores of iter j-1 (+4 loads of c[j+1] if issued).
        if (j == 0) { if (nact > 1) VMW(4); else VMW(0); }
        else        { if (j + 1 < nact) VMW(20); else VMW(16); }
        __builtin_amdgcn_s_barrier(); SB();

        v4f acc[2][2];
#pragma unroll
        for (int mt = 0; mt < 2; ++mt)
#pragma unroll
            for (int nt = 0; nt < 2; ++nt)
                acc[mt][nt] = (v4f){0.f, 0.f, 0.f, 0.f};

        const char* xb = &Xs[cb][0][0];
#pragma unroll
        for (int kk = 0; kk < 8; ++kk) {
            v8s af[2];
#pragma unroll
            for (int mt = 0; mt < 2; ++mt) {
                const int row = wm * 32 + mt * 16 + l16;
                const int sw  = (row & 7) << 4;
                const char* pr = xb + row * 1024;
                v4f f0 = *(const v4f*)(pr + ((kk * 128 + quad * 32) ^ sw));
                v4f f1 = *(const v4f*)(pr + ((kk * 128 + quad * 32 + 16) ^ sw));
                union { v8s s; unsigned int w[4]; } u;
                asm("v_cvt_pk_bf16_f32 %0, %1, %2" : "=v"(u.w[0]) : "v"(f0[0]), "v"(f0[1]));
                asm("v_cvt_pk_bf16_f32 %0, %1, %2" : "=v"(u.w[1]) : "v"(f0[2]), "v"(f0[3]));
                asm("v_cvt_pk_bf16_f32 %0, %1, %2" : "=v"(u.w[2]) : "v"(f1[0]), "v"(f1[1]));
                asm("v_cvt_pk_bf16_f32 %0, %1, %2" : "=v"(u.w[3]) : "v"(f1[2]), "v"(f1[3]));
                af[mt] = u.s;
            }
#pragma unroll
            for (int mt = 0; mt < 2; ++mt)
#pragma unroll
                for (int nt = 0; nt < 2; ++nt)
                    acc[mt][nt] = __builtin_amdgcn_mfma_f32_16x16x32_bf16(
                        af[mt], B[nt][kk >> 1][kk & 1], acc[mt][nt], 0, 0, 0);
        }

        // epilogue: (+b1 user side), bf16 store; UNIFORM 16 stores/wave (padded P/Q)
#pragma unroll
        for (int mt = 0; mt < 2; ++mt)
#pragma unroll
            for (int j4 = 0; j4 < 4; ++j4) {
                const long m = m0 + wm * 32 + mt * 16 + quad * 4 + j4;
#pragma unroll
                for (int nt = 0; nt < 2; ++nt)
                    outp[(size_t)m * H + wn * 32 + nt * 16 + l16] =
                        f2bf(acc[mt][nt][j4] + bv[nt]);
            }
        SB();
        __builtin_amdgcn_s_barrier(); SB();
        if (j + 2 < nact) STAGE(nextc(pf), cb);   // reuse buf[cb]; stays in flight
    }
}

// ---- edge pass: out[e] = relu(P[u] + Q[m]) . w2 + b2 ----
// block 256 thr = 8 half-waves; each half-wave does 8 edges; row loads
// double-buffered. R1-verified best config: single dispatch, 8 waves/EU,
// 68.6us @ 72% occupancy, 3.5 TB/s sustained random-row gather (throughput-
// wall: R2 occupancy-halving null; bank conflicts 0).
__global__ __launch_bounds__(256, 8) void edge_score_kernel(
    const unsigned short* __restrict__ P,
    const unsigned short* __restrict__ Q,
    const int* __restrict__ eli,
    const float* __restrict__ w2,
    const float* __restrict__ b2,
    float* __restrict__ out,
    const int E, const int n_users, const int n_movies)
{
    const int t   = threadIdx.x;
    const int hw  = t >> 5;        // 0..7
    const int l32 = t & 31;

    float w2v[8];
    {
        v4f a = *(const v4f*)(w2 + l32 * 8);
        v4f b = *(const v4f*)(w2 + l32 * 8 + 4);
#pragma unroll
        for (int i = 0; i < 4; ++i) { w2v[i] = a[i]; w2v[4 + i] = b[i]; }
    }
    const float b2v = b2[0];
    const long base = (long)blockIdx.x * 64;

    // preload all 16 indices (independent loads issue together)
    int us[8], ms[8];
#pragma unroll
    for (int i = 0; i < 8; ++i) {
        long e = base + i * 8 + hw;
        long ec = (e < E) ? e : 0;
        int u = eli[ec];
        int m = eli[(long)E + ec];
        us[i] = u < 0 ? 0 : (u >= n_users  ? n_users  - 1 : u);
        ms[i] = m < 0 ? 0 : (m >= n_movies ? n_movies - 1 : m);
    }

    v8s pv = *(const v8s*)(P + (size_t)us[0] * H + l32 * 8);
    v8s qv = *(const v8s*)(Q + (size_t)ms[0] * H + l32 * 8);

#pragma unroll
    for (int i = 0; i < 8; ++i) {
        v8s pn, qn;
        if (i < 7) {                                   // next rows issue before compute
            pn = *(const v8s*)(P + (size_t)us[i + 1] * H + l32 * 8);
            qn = *(const v8s*)(Q + (size_t)ms[i + 1] * H + l32 * 8);
        }
        float s = 0.f;
#pragma unroll
        for (int j = 0; j < 8; ++j) {
            float h = bf2f((unsigned short)pv[j]) + bf2f((unsigned short)qv[j]);
            h = h > 0.f ? h : 0.f;
            s += h * w2v[j];
        }
        s += __shfl_xor(s, 1, 64);
        s += __shfl_xor(s, 2, 64);
        s += __shfl_xor(s, 4, 64);
        s += __shfl_xor(s, 8, 64);
        s += __shfl_xor(s, 16, 64);
        long e = base + i * 8 + hw;
        if (l32 == 0 && e < E) out[e] = s + b2v;
        pv = pn; qv = qn;
    }
}

// ================= round-6 fallback (verified) — used if ws_size too small ==========
constexpr int BMF = 64;
__global__ __launch_bounds__(512, 4) void edge_decoder_kernel(
    const float* __restrict__ user_emb, const float* __restrict__ movie_emb,
    const int* __restrict__ eli, const unsigned short* __restrict__ w1t,
    const float* __restrict__ b1, const float* __restrict__ w2,
    const float* __restrict__ b2, float* __restrict__ out,
    const int E, const int n_users, const int n_movies)
{
    __shared__ unsigned short Xs[BMF * XS];
    __shared__ unsigned short Wts[H * WS];
    __shared__ float red[4][BMF];
    const int t = threadIdx.x, wave = t >> 6, lane = t & 63;
    const int wm = wave >> 2, wn = wave & 3, quad = lane >> 4, l16 = lane & 15;
    const long e0 = (long)blockIdx.x * BMF;
    const int xr = t >> 3, xc = t & 7;
    long eg = e0 + xr; if (eg >= E) eg = 0;
    int iu = eli[eg], im = eli[(long)E + eg];
    iu = iu < 0 ? 0 : (iu >= n_users ? n_users - 1 : iu);
    im = im < 0 ? 0 : (im >= n_movies ? n_movies - 1 : im);
    const float* urow = user_emb + (size_t)iu * H;
    const float* mrow = movie_emb + (size_t)im * H;
    const int wr = t >> 3, wc8 = t & 7;
    const unsigned short* wbase = w1t + (size_t)wr * K2 + wc8 * 8;
    v4f acc[2][4];
#pragma unroll
    for (int mt = 0; mt < 2; ++mt)
#pragma unroll
        for (int nt = 0; nt < 4; ++nt) acc[mt][nt] = (v4f){0.f,0.f,0.f,0.f};
    v4f xq0 = *(const v4f*)(urow + xc * 8);
    v4f xq1 = *(const v4f*)(urow + xc * 8 + 4);
    v8s wq[4];
#pragma unroll
    for (int j = 0; j < 4; ++j) wq[j] = *(const v8s*)(wbase + (size_t)j * 64 * K2);
    for (int kt = 0; kt < 8; ++kt) {
        __syncthreads();
        { v8s xv;
#pragma unroll
          for (int i = 0; i < 4; ++i) xv[i] = (short)f2bf(xq0[i]);
#pragma unroll
          for (int i = 0; i < 4; ++i) xv[4+i] = (short)f2bf(xq1[i]);
          *(v8s*)(Xs + xr * XS + xc * 8) = xv; }
#pragma unroll
        for (int j = 0; j < 4; ++j) *(v8s*)(Wts + (j * 64 + wr) * WS + wc8 * 8) = wq[j];
        if (kt < 7) {
            const int kn = kt + 1, koff = (kn * 64) & 255;
            const float* src = ((kn < 4) ? urow : mrow) + koff + xc * 8;
            xq0 = *(const v4f*)(src); xq1 = *(const v4f*)(src + 4);
#pragma unroll
            for (int j = 0; j < 4; ++j) wq[j] = *(const v8s*)(wbase + (size_t)j * 64 * K2 + kn * 64);
        }
        __syncthreads();
#pragma unroll
        for (int ks = 0; ks < 2; ++ks) {
            v8s af[2], bf[4];
#pragma unroll
            for (int mt = 0; mt < 2; ++mt)
                af[mt] = *(const v8s*)(Xs + (wm * 32 + mt * 16 + l16) * XS + ks * 32 + quad * 8);
#pragma unroll
            for (int nt = 0; nt < 4; ++nt)
                bf[nt] = *(const v8s*)(Wts + (wn * 64 + nt * 16 + l16) * WS + ks * 32 + quad * 8);
#pragma unroll
            for (int mt = 0; mt < 2; ++mt)
#pragma unroll
                for (int nt = 0; nt < 4; ++nt)
                    acc[mt][nt] = __builtin_amdgcn_mfma_f32_16x16x32_bf16(af[mt], bf[nt], acc[mt][nt], 0, 0, 0);
        }
    }
    float b1v[4], w2v[4];
#pragma unroll
    for (int nt = 0; nt < 4; ++nt) {
        int n = wn * 64 + nt * 16 + l16;
        b1v[nt] = b1[n]; w2v[nt] = w2[n];
    }
    const float b2v = b2[0];
#pragma unroll
    for (int mt = 0; mt < 2; ++mt) {
        float s[4] = {0.f,0.f,0.f,0.f};
#pragma unroll
        for (int nt = 0; nt < 4; ++nt)
#pragma unroll
            for (int j = 0; j < 4; ++j) {
                float h = acc[mt][nt][j] + b1v[nt];
                h = h > 0.f ? h : 0.f;
                s[j] += h * w2v[nt];
            }
#pragma unroll
        for (int j = 0; j < 4; ++j) {
            float v = s[j];
            v += __shfl_xor(v, 1, 64); v += __shfl_xor(v, 2, 64);
            v += __shfl_xor(v, 4, 64); v += __shfl_xor(v, 8, 64);
            if (l16 == 0) red[wn][wm * 32 + mt * 16 + quad * 4 + j] = v;
        }
    }
    __syncthreads();
    if (t < BMF) {
        long e = e0 + t;
        if (e < E) out[e] = red[0][t] + red[1][t] + red[2][t] + red[3][t] + b2v;
    }
}

extern "C" void kernel_launch(void* const* d_in, const int* in_sizes, int n_in,
                              void* d_out, int out_size, void* d_ws, size_t ws_size,
                              hipStream_t stream) {
    const float* user_emb  = (const float*)d_in[0];
    const float* movie_emb = (const float*)d_in[1];
    const int*   eli       = (const int*)d_in[2];
    const float* w1        = (const float*)d_in[3];
    const float* b1        = (const float*)d_in[4];
    const float* w2        = (const float*)d_in[5];
    const float* b2        = (const float*)d_in[6];
    float*       out       = (float*)d_out;

    const int E        = out_size;
    const int n_users  = in_sizes[0] / H;
    const int n_movies = in_sizes[1] / H;

    unsigned short* w1t = (unsigned short*)d_ws;                 // 256 KiB
    const size_t w1t_bytes = (size_t)K2 * H * 2;
    const size_t p_bytes   = (size_t)(n_users  + 64) * H * 2;    // +64 pad rows
    const size_t q_bytes   = (size_t)(n_movies + 64) * H * 2;    // (uniform epilogue)

    const int nbu = (n_users  + 63) / 64;
    const int nbm = (n_movies + 63) / 64;
    const size_t flag_bytes = (size_t)nbu + (size_t)nbm;

    // persistent path needs: w1t + padded P + padded Q + flags, and chunk counts
    // within the per-block ballot capacity (64 mask bits x 128 blocks/side)
    if (ws_size >= w1t_bytes + p_bytes + q_bytes + flag_bytes &&
        nbu <= 64 * 128 && nbm <= 64 * 128) {
        unsigned short* P = (unsigned short*)((char*)d_ws + w1t_bytes);
        unsigned short* Q = (unsigned short*)((char*)d_ws + w1t_bytes + p_bytes);
        unsigned char*  fu = (unsigned char*)((char*)d_ws + w1t_bytes + p_bytes + q_bytes);
        unsigned char*  fm = fu + nbu;

        w1_transpose_kernel<<<dim3(16, 8), 256, 0, stream>>>(w1, w1t, fu, nbu + nbm);
        if (E > 0)
            flag_fill_kernel<<<512, 256, 0, stream>>>(eli, fu, fm, E, n_users, n_movies);
        emb_gemm_persist_kernel<<<256, 1024, 0, stream>>>(
            user_emb, movie_emb, w1t, b1, P, Q, n_users, n_movies, fu, fm);
        if (E > 0)
            edge_score_kernel<<<(E + 63) / 64, 256, 0, stream>>>(
                P, Q, eli, w2, b2, out, E, n_users, n_movies);
    } else {
        w1_transpose_kernel<<<dim3(16, 8), 256, 0, stream>>>(w1, w1t, nullptr, 0);
        if (E > 0)
            edge_decoder_kernel<<<(E + BMF - 1) / BMF, 512, 0, stream>>>(
                user_emb, movie_emb, eli, w1t, b1, w2, b2, out, E, n_users, n_movies);
    }
}